// Round 1
// baseline (679.990 us; speedup 1.0000x reference)
//
#include <hip/hip_runtime.h>
#include <hip/hip_bf16.h>

#define DEVI __device__ __forceinline__

typedef short bf16x8 __attribute__((ext_vector_type(8)));
typedef float f32x4 __attribute__((ext_vector_type(4)));

// ---- helpers -------------------------------------------------------------

DEVI unsigned short f2b(float f) {  // f32 -> bf16 bits, RNE
    union { float f; unsigned u; } x; x.f = f;
    unsigned r = x.u + 0x7fffu + ((x.u >> 16) & 1u);
    return (unsigned short)(r >> 16);
}

DEVI float b2f(unsigned short u) {
    union { unsigned u; float f; } x; x.u = ((unsigned)u) << 16; return x.f;
}

DEVI void gld_lds16(const void* g, void* l) {
    __builtin_amdgcn_global_load_lds(
        (const __attribute__((address_space(1))) void*)g,
        (__attribute__((address_space(3))) void*)l, 16, 0, 0);
}

// ---- f32 -> bf16 convert (vectorized, grid-stride) -----------------------

__global__ __launch_bounds__(256) void cvt_f32_bf16(
    const float* __restrict__ src, unsigned short* __restrict__ dst, int n4)
{
    int stride = gridDim.x * 256;
    for (int i = blockIdx.x * 256 + threadIdx.x; i < n4; i += stride) {
        float4 v = reinterpret_cast<const float4*>(src)[i];
        ushort4 o;
        o.x = f2b(v.x); o.y = f2b(v.y); o.z = f2b(v.z); o.w = f2b(v.w);
        reinterpret_cast<ushort4*>(dst)[i] = o;
    }
}

// ---- GEMM: C[M,N] = A[M,K] @ B[N,K]^T + bias[N] (+resid) -----------------
// tile 128x128, BK=32, 4 waves, double-buffered global_load_lds staging.
// EPI: 0 = f32 out, 1 = bf16 out, 2 = bf16 out with f32 residual add.
// M % 128 == 0, N % 128 == 0, K % 32 == 0 (all true for this problem).

template<int EPI>
__global__ __launch_bounds__(256) void gemm_bt(
    const unsigned short* __restrict__ A, const unsigned short* __restrict__ Bm,
    const float* __restrict__ bias, const float* resid,
    float* outF, unsigned short* outB,
    int Mn, int Nn, int K, int mtiles)
{
    __shared__ short lds[2][2][128 * 32];
    const int tid = threadIdx.x;
    const int lane = tid & 63, w = tid >> 6;
    const int bid = blockIdx.x;
    const int mt = bid % mtiles, nt = bid / mtiles;
    const int m0 = mt * 128, n0 = nt * 128;
    const int fr = lane & 15, kg = lane >> 4;
    const int wr = (w >> 1) * 64, wc = (w & 1) * 64;

    auto stage = [&](int buf, int k0) {
        // A tile: 128x32 bf16 = 512 x 16B slots, 2 rounds of 256 threads
#pragma unroll
        for (int rnd = 0; rnd < 2; ++rnd) {
            int chunk = rnd * 256 + w * 64;      // wave-uniform
            int slot = chunk + lane;
            int row = slot >> 2, ks = slot & 3;
            gld_lds16(A + (size_t)(m0 + row) * K + k0 + ks * 8,
                      (void*)&lds[buf][0][chunk * 8]);
        }
#pragma unroll
        for (int rnd = 0; rnd < 2; ++rnd) {
            int chunk = rnd * 256 + w * 64;
            int slot = chunk + lane;
            int row = slot >> 2, ks = slot & 3;
            gld_lds16(Bm + (size_t)(n0 + row) * K + k0 + ks * 8,
                      (void*)&lds[buf][1][chunk * 8]);
        }
    };

    f32x4 acc[4][4] = {};

    stage(0, 0);
    __syncthreads();
    const int nk = K >> 5;
    for (int kt = 0; kt < nk; ++kt) {
        int buf = kt & 1;
        if (kt + 1 < nk) stage(buf ^ 1, (kt + 1) * 32);
        const short* As = lds[buf][0];
        const short* Bs = lds[buf][1];
        bf16x8 af[4], bfv[4];
#pragma unroll
        for (int m = 0; m < 4; ++m)
            af[m] = *(const bf16x8*)&As[(wr + m * 16 + fr) * 32 + kg * 8];
#pragma unroll
        for (int n = 0; n < 4; ++n)
            bfv[n] = *(const bf16x8*)&Bs[(wc + n * 16 + fr) * 32 + kg * 8];
#pragma unroll
        for (int m = 0; m < 4; ++m)
#pragma unroll
            for (int n = 0; n < 4; ++n)
                acc[m][n] = __builtin_amdgcn_mfma_f32_16x16x32_bf16(
                    af[m], bfv[n], acc[m][n], 0, 0, 0);
        __syncthreads();
    }

    // epilogue: D[row][col], col = lane&15, row = (lane>>4)*4 + reg
#pragma unroll
    for (int n = 0; n < 4; ++n) {
        int col = n0 + wc + n * 16 + fr;
        float bc = bias[col];
#pragma unroll
        for (int m = 0; m < 4; ++m) {
            f32x4 v = acc[m][n];
#pragma unroll
            for (int i = 0; i < 4; ++i) {
                int row = m0 + wr + m * 16 + kg * 4 + i;
                size_t idx = (size_t)row * Nn + col;
                float val = v[i] + bc;
                if (EPI == 0) {
                    outF[idx] = val;
                } else if (EPI == 1) {
                    outB[idx] = f2b(val);
                } else {
                    val += resid[idx];
                    outB[idx] = f2b(val);
                }
            }
        }
    }
}

// ---- l2norm over last dim (1024) + broadcast-add oimages -----------------
// one block per row; in-place on f32 buffer is safe (each thread RMW its slot)

__global__ __launch_bounds__(256) void l2norm_add(
    const float* fin, const float* __restrict__ oimg,
    float* foutF, unsigned short* __restrict__ foutB)
{
    int row = blockIdx.x;          // 0..9215  (b*36+n)
    int b = row / 36;
    float4 v = reinterpret_cast<const float4*>(fin + (size_t)row * 1024)[threadIdx.x];
    float s = v.x * v.x + v.y * v.y + v.z * v.z + v.w * v.w;
#pragma unroll
    for (int o = 32; o; o >>= 1) s += __shfl_down(s, o, 64);
    __shared__ float ws4[4];
    int lane = threadIdx.x & 63, w = threadIdx.x >> 6;
    if (lane == 0) ws4[w] = s;
    __syncthreads();
    float tot = ws4[0] + ws4[1] + ws4[2] + ws4[3];
    float inv = 1.0f / (sqrtf(tot) + 1e-8f);
    float4 o4 = reinterpret_cast<const float4*>(oimg + (size_t)b * 1024)[threadIdx.x];
    float4 y;
    y.x = v.x * inv + o4.x; y.y = v.y * inv + o4.y;
    y.z = v.z * inv + o4.z; y.w = v.w * inv + o4.w;
    reinterpret_cast<float4*>(foutF + (size_t)row * 1024)[threadIdx.x] = y;
    ushort4 yb; yb.x = f2b(y.x); yb.y = f2b(y.y); yb.z = f2b(y.z); yb.w = f2b(y.w);
    reinterpret_cast<ushort4*>(foutB + (size_t)row * 1024)[threadIdx.x] = yb;
}

// ---- GRU step: gh = h @ whh^T + bhh; gate math; ping-pong h ---------------
// grid 256 = 4 batch-tiles(64) x 64 col-tiles(16). Per block: 64x16 outputs,
// 3 gates -> 48 whh rows. 4 waves: wave w owns batches [w*16, w*16+16).

__global__ __launch_bounds__(256) void gru_step(
    const unsigned short* __restrict__ hb, const float* __restrict__ hf,
    const unsigned short* __restrict__ whh, const unsigned short* __restrict__ gi,
    const float* __restrict__ bhh,
    float* __restrict__ hfo, unsigned short* __restrict__ hbo, int t)
{
    __shared__ short lds[2][64 * 32 + 48 * 32];
    const int tid = threadIdx.x, lane = tid & 63, w = tid >> 6;
    const int bid = blockIdx.x;
    const int b0 = (bid & 3) * 64;
    const int e0 = (bid >> 2) * 16;
    const int fr = lane & 15, kg = lane >> 4;

    auto stage = [&](int buf, int k0) {
        {   // h tile 64x32: 256 slots, one round
            int chunk = w * 64, slot = chunk + lane;
            int row = slot >> 2, ks = slot & 3;
            gld_lds16(hb + (size_t)(b0 + row) * 1024 + k0 + ks * 8,
                      (void*)&lds[buf][chunk * 8]);
        }
        if (w < 3) {  // whh tile 48x32: 192 slots, waves 0..2
            int chunk = w * 64, slot = chunk + lane;
            int j = slot >> 2, ks = slot & 3;
            int g = j >> 4, c = j & 15;
            gld_lds16(whh + (size_t)(g * 1024 + e0 + c) * 1024 + k0 + ks * 8,
                      (void*)&lds[buf][64 * 32 + chunk * 8]);
        }
    };

    f32x4 acc[3] = {};
    stage(0, 0);
    __syncthreads();
    for (int kt = 0; kt < 32; ++kt) {
        int buf = kt & 1;
        if (kt < 31) stage(buf ^ 1, (kt + 1) * 32);
        const short* Hs = lds[buf];
        const short* Ws = lds[buf] + 64 * 32;
        bf16x8 a = *(const bf16x8*)&Hs[(w * 16 + fr) * 32 + kg * 8];
#pragma unroll
        for (int g = 0; g < 3; ++g) {
            bf16x8 bb = *(const bf16x8*)&Ws[(g * 16 + fr) * 32 + kg * 8];
            acc[g] = __builtin_amdgcn_mfma_f32_16x16x32_bf16(a, bb, acc[g], 0, 0, 0);
        }
        __syncthreads();
    }

    const int e = e0 + fr;
    const float bhr = bhh[e], bhz = bhh[1024 + e], bhn = bhh[2048 + e];
#pragma unroll
    for (int i = 0; i < 4; ++i) {
        int b = b0 + w * 16 + kg * 4 + i;
        const unsigned short* gir = gi + ((size_t)b * 36 + t) * 3072;
        float ir = b2f(gir[e]), iz = b2f(gir[1024 + e]), inn = b2f(gir[2048 + e]);
        float ghr = acc[0][i] + bhr;
        float ghz = acc[1][i] + bhz;
        float ghn = acc[2][i] + bhn;
        float r = 1.f / (1.f + __expf(-(ir + ghr)));
        float z = 1.f / (1.f + __expf(-(iz + ghz)));
        float n = tanhf(inn + r * ghn);
        float hold = hf[(size_t)b * 1024 + e];
        float hnew = (1.f - z) * n + z * hold;
        hfo[(size_t)b * 1024 + e] = hnew;
        hbo[(size_t)b * 1024 + e] = f2b(hnew);
    }
}

__global__ __launch_bounds__(256) void zero_h(float* hf0, unsigned short* hb0) {
    int i = blockIdx.x * 256 + threadIdx.x;   // 1024 blocks -> 262144
    hf0[i] = 0.f;
    hb0[i] = 0;
}

__global__ __launch_bounds__(256) void final_norm(
    const float* __restrict__ hf, float* __restrict__ out)
{
    int row = blockIdx.x;   // 0..255
    float4 v = reinterpret_cast<const float4*>(hf + (size_t)row * 1024)[threadIdx.x];
    float s = v.x * v.x + v.y * v.y + v.z * v.z + v.w * v.w;
#pragma unroll
    for (int o = 32; o; o >>= 1) s += __shfl_down(s, o, 64);
    __shared__ float ws4[4];
    int lane = threadIdx.x & 63, w = threadIdx.x >> 6;
    if (lane == 0) ws4[w] = s;
    __syncthreads();
    float tot = ws4[0] + ws4[1] + ws4[2] + ws4[3];
    float inv = 1.0f / (sqrtf(tot) + 1e-8f);
    float4 y; y.x = v.x * inv; y.y = v.y * inv; y.z = v.z * inv; y.w = v.w * inv;
    reinterpret_cast<float4*>(out + (size_t)row * 1024)[threadIdx.x] = y;
}

// ---- launch ---------------------------------------------------------------

extern "C" void kernel_launch(void* const* d_in, const int* in_sizes, int n_in,
                              void* d_out, int out_size, void* d_ws, size_t ws_size,
                              hipStream_t stream)
{
    constexpr int cB = 256, cN = 36, cIMG = 2048, cE = 1024, cH3 = 3072;
    constexpr int cM = cB * cN;  // 9216

    const float* images  = (const float*)d_in[0];
    const float* oimages = (const float*)d_in[1];
    const float* wl_w    = (const float*)d_in[2];
    const float* wl_b    = (const float*)d_in[3];
    // d_in[4..7]: wk_w, wk_b, wq_w, wq_b — dead (softmax row-sums == 1)
    const float* wv_w    = (const float*)d_in[8];
    const float* wv_b    = (const float*)d_in[9];
    const float* wih     = (const float*)d_in[10];
    const float* whh     = (const float*)d_in[11];
    const float* bih     = (const float*)d_in[12];
    const float* bhh     = (const float*)d_in[13];

    char* ws = (char*)d_ws;
    size_t off = 0;
    auto alloc = [&](size_t bytes) -> char* {
        char* p = ws + off; off += (bytes + 255) & ~(size_t)255; return p;
    };
    unsigned short* imgB = (unsigned short*)alloc((size_t)cM * cIMG * 2);
    unsigned short* wlB  = (unsigned short*)alloc((size_t)cE * cIMG * 2);
    unsigned short* wvB  = (unsigned short*)alloc((size_t)cE * cE * 2);
    unsigned short* wihB = (unsigned short*)alloc((size_t)cH3 * cE * 2);
    unsigned short* whhB = (unsigned short*)alloc((size_t)cH3 * cE * 2);
    float*          fpre = (float*)alloc((size_t)cM * cE * 4);
    unsigned short* fB   = (unsigned short*)alloc((size_t)cM * cE * 2);
    unsigned short* f2B  = (unsigned short*)alloc((size_t)cM * cE * 2);
    unsigned short* giB  = (unsigned short*)alloc((size_t)cM * cH3 * 2);
    float*          hf0  = (float*)alloc((size_t)cB * cE * 4);
    float*          hf1  = (float*)alloc((size_t)cB * cE * 4);
    unsigned short* hb0  = (unsigned short*)alloc((size_t)cB * cE * 2);
    unsigned short* hb1  = (unsigned short*)alloc((size_t)cB * cE * 2);
    (void)ws_size;

    // bf16 conversions
    cvt_f32_bf16<<<2048, 256, 0, stream>>>(images, imgB, cM * cIMG / 4);
    cvt_f32_bf16<<<512, 256, 0, stream>>>(wl_w, wlB, cE * cIMG / 4);
    cvt_f32_bf16<<<256, 256, 0, stream>>>(wv_w, wvB, cE * cE / 4);
    cvt_f32_bf16<<<512, 256, 0, stream>>>(wih, wihB, cH3 * cE / 4);
    cvt_f32_bf16<<<512, 256, 0, stream>>>(whh, whhB, cH3 * cE / 4);

    // G1: fpre = images @ wl_w^T + wl_b            (9216x1024, K=2048)
    gemm_bt<0><<<72 * 8, 256, 0, stream>>>(imgB, wlB, wl_b, nullptr,
                                           fpre, nullptr, cM, cE, cIMG, 72);
    // f = l2norm(fpre) + oimages  (in-place f32 + bf16 shadow)
    l2norm_add<<<cM, 256, 0, stream>>>(fpre, oimages, fpre, fB);

    // G2: f2 = f @ wv_w^T + wv_b + f               (attn == v shortcut)
    gemm_bt<2><<<72 * 8, 256, 0, stream>>>(fB, wvB, wv_b, fpre,
                                           nullptr, f2B, cM, cE, cE, 72);
    // G3: gi = f2 @ gru_wih^T + bih                (9216x3072, K=1024)
    gemm_bt<1><<<72 * 24, 256, 0, stream>>>(f2B, wihB, bih, nullptr,
                                            nullptr, giB, cM, cH3, cE, 72);

    zero_h<<<1024, 256, 0, stream>>>(hf0, hb0);
    float* hfp[2] = { hf0, hf1 };
    unsigned short* hbp[2] = { hb0, hb1 };
    for (int t = 0; t < 36; ++t) {
        gru_step<<<256, 256, 0, stream>>>(hbp[t & 1], hfp[t & 1], whhB, giB, bhh,
                                          hfp[(t + 1) & 1], hbp[(t + 1) & 1], t);
    }
    // out = l2norm(h_36)  — final state lives in buffer 0 (36 is even)
    final_norm<<<cB, 256, 0, stream>>>(hf0, (float*)d_out);
}